// Round 3
// baseline (469.583 us; speedup 1.0000x reference)
//
#include <hip/hip_runtime.h>
#include <hip/hip_bf16.h>
#include <math.h>

// fragment types
typedef __attribute__((ext_vector_type(8))) short bfrag;    // 8 bf16
typedef __attribute__((ext_vector_type(4))) short short4v;  // 4 bf16
typedef __attribute__((ext_vector_type(4))) float f32x4;

#define LDK 136  // padded LDS row length in bf16 elems (272B rows, 16B-aligned)

// exact bf16(bits-in-short) -> f32
static __device__ __forceinline__ float b2f(short s)
{
    unsigned int u = ((unsigned int)(unsigned short)s) << 16;
    float f;
    __builtin_memcpy(&f, &u, 4);
    return f;
}

static __device__ __forceinline__ short4v pack4(f32x4 a)
{
    short4v o;
#pragma unroll
    for (int r = 0; r < 4; ++r) {
        __hip_bfloat16 h = __float2bfloat16(a[r]);
        short s;
        __builtin_memcpy(&s, &h, 2);
        o[r] = s;
    }
    return o;
}

static __device__ __forceinline__ bfrag pack8(f32x4 a, f32x4 b)
{
    bfrag o;
#pragma unroll
    for (int j = 0; j < 4; ++j) {
        __hip_bfloat16 h = __float2bfloat16(a[j]);
        short s;
        __builtin_memcpy(&s, &h, 2);
        o[j] = s;
    }
#pragma unroll
    for (int j = 0; j < 4; ++j) {
        __hip_bfloat16 h = __float2bfloat16(b[j]);
        short s;
        __builtin_memcpy(&s, &h, 2);
        o[4 + j] = s;
    }
    return o;
}

// ---------------------------------------------------------------------------
// Prep: W[128][128] fp32 -> bf16 transposed WT[n][k].  (unchanged, verified)
// Order in ws: 0=Wq 1=Wk 2=Wv 3=Wo 4=W1 5=W2 6=Wq_s 7=Wk_s
// ---------------------------------------------------------------------------
__global__ __launch_bounds__(256) void prep_weights(
    const float* __restrict__ Wq, const float* __restrict__ Wk,
    const float* __restrict__ Wv, const float* __restrict__ Wo,
    const float* __restrict__ W1, const float* __restrict__ W2,
    const float* __restrict__ Wqs, const float* __restrict__ Wks,
    __hip_bfloat16* __restrict__ out)
{
    __shared__ __hip_bfloat16 t[128 * 17];
    const float* Ws[8] = {Wq, Wk, Wv, Wo, W1, W2, Wqs, Wks};
    const int mat = blockIdx.x >> 3;
    const int slab = blockIdx.x & 7;
    const float* W = Ws[mat];
    const int n0 = slab * 16;
    __hip_bfloat16* o = out + (size_t)mat * 16384 + (size_t)n0 * 128;

#pragma unroll
    for (int p = 0; p < 2; ++p) {
        int idx = p * 256 + threadIdx.x;
        int k = idx >> 2, c4 = idx & 3;
        float4 f = *(const float4*)(W + k * 128 + n0 + c4 * 4);
        __hip_bfloat16* d = t + k * 17 + c4 * 4;
        d[0] = __float2bfloat16(f.x); d[1] = __float2bfloat16(f.y);
        d[2] = __float2bfloat16(f.z); d[3] = __float2bfloat16(f.w);
    }
    __syncthreads();
    {
        int n = threadIdx.x >> 4;
        int k0 = (threadIdx.x & 15) * 8;
        __hip_bfloat16 v[8];
#pragma unroll
        for (int j = 0; j < 8; ++j) v[j] = t[(k0 + j) * 17 + n];
        *(bfrag*)(o + n * 128 + k0) = *(const bfrag*)v;
    }
}

// ---------------------------------------------------------------------------
// One-wave 16x128 @ 128x128 matmuls. x[kk] = X[m][kk*32+quad*8 .. +8].
// mmT8: acc[ct][r] = OUT[m][ct*16+quad*4+r]       (col-group layout)
// mmR8: acc[ct][r] = OUT[quad*4+r][ct*16+m]       (row layout; V only)
// ---------------------------------------------------------------------------
__device__ __forceinline__ void mmT8(const bfrag x[4],
                                     const __hip_bfloat16* __restrict__ wT,
                                     int m, int quad, f32x4 acc[8])
{
    const f32x4 z = {0.f, 0.f, 0.f, 0.f};
#pragma unroll
    for (int ct = 0; ct < 8; ++ct) acc[ct] = z;
#pragma unroll
    for (int kk = 0; kk < 4; ++kk)
#pragma unroll
        for (int ct = 0; ct < 8; ++ct) {
            bfrag w = *(const bfrag*)(wT + (size_t)(ct * 16 + m) * 128 + kk * 32 + quad * 8);
            acc[ct] = __builtin_amdgcn_mfma_f32_16x16x32_bf16(w, x[kk], acc[ct], 0, 0, 0);
        }
}

__device__ __forceinline__ void mmR8(const bfrag x[4],
                                     const __hip_bfloat16* __restrict__ wT,
                                     int m, int quad, f32x4 acc[8])
{
    const f32x4 z = {0.f, 0.f, 0.f, 0.f};
#pragma unroll
    for (int ct = 0; ct < 8; ++ct) acc[ct] = z;
#pragma unroll
    for (int kk = 0; kk < 4; ++kk)
#pragma unroll
        for (int ct = 0; ct < 8; ++ct) {
            bfrag w = *(const bfrag*)(wT + (size_t)(ct * 16 + m) * 128 + kk * 32 + quad * 8);
            acc[ct] = __builtin_amdgcn_mfma_f32_16x16x32_bf16(x[kk], w, acc[ct], 0, 0, 0);
        }
}

// ---------------------------------------------------------------------------
// fused model: ONE WAVE PER BATCH. 64-thread blocks, zero __syncthreads.
// All operands register-resident except 4 intra-wave LDS re-layouts
// (O, H, F1, CAC: col-group -> k-slice), ordered by in-wave DS ordering.
// ---------------------------------------------------------------------------
__global__ __launch_bounds__(64) void fused_model(
    const float* __restrict__ agent_embed,   // [B,16,128]
    const float* __restrict__ city_embed,    // [B,128,128]
    const int* __restrict__ acts,            // [B,16]
    const __hip_bfloat16* __restrict__ wts,  // 8 x WT[128][128] bf16
    const float* __restrict__ ln1g, const float* __restrict__ ln1b,
    const float* __restrict__ b1, const float* __restrict__ b2,
    const float* __restrict__ ln2g, const float* __restrict__ ln2b,
    float* __restrict__ out)                 // [B,16,16]
{
    __shared__ __align__(16) __hip_bfloat16 sb[16 * LDK];  // re-layout buffer

    const int lane = threadIdx.x & 63;
    const int m = lane & 15;
    const int quad = lane >> 4;
    const int b = blockIdx.x;

    // ---- masks: conflict(q=m, k'=quad*4+r) ----
    const int aq = acts[b * 16 + m];   // acts[q] for q = m (also the gather row)
    bool keep[4];
#pragma unroll
    for (int r = 0; r < 4; ++r) {
        int ak = __shfl(aq, quad * 4 + r, 16);  // acts[quad*4+r]
        keep[r] = (aq == 0) ? (quad * 4 + r == m) : (ak == aq);
    }

    // ---- inputs: agent row m (k-slice), selected city row (k-slice + col-group) ----
    const float* arow = agent_embed + ((size_t)b * 16 + m) * 128;
    const float* crow = city_embed + ((size_t)b * 128 + aq) * 128;
    bfrag xa[4], xsk[4];
#pragma unroll
    for (int kk = 0; kk < 4; ++kk) {
        f32x4 a0 = *(const f32x4*)(arow + kk * 32 + quad * 8);
        f32x4 a1 = *(const f32x4*)(arow + kk * 32 + quad * 8 + 4);
        xa[kk] = pack8(a0, a1);
        f32x4 c0 = *(const f32x4*)(crow + kk * 32 + quad * 8);
        f32x4 c1 = *(const f32x4*)(crow + kk * 32 + quad * 8 + 4);
        xsk[kk] = pack8(c0, c1);
    }
    short4v xsr[8];  // selected, col-group layout (residual in S6)
#pragma unroll
    for (int ct = 0; ct < 8; ++ct)
        xsr[ct] = pack4(*(const f32x4*)(crow + ct * 16 + quad * 4));

    f32x4 acc[8];
    short4v kf[8], vf[8], ksf[8], qf[8];

    // ---- S1: K = agent @ Wk   (col-group == 16x16x16 A-frag) ----
    mmT8(xa, wts + 1 * 16384, m, quad, acc);
#pragma unroll
    for (int ct = 0; ct < 8; ++ct) kf[ct] = pack4(acc[ct]);
    // ---- S2: V = agent @ Wv   (row layout == PV A-frag) ----
    mmR8(xa, wts + 2 * 16384, m, quad, acc);
#pragma unroll
    for (int ct = 0; ct < 8; ++ct) vf[ct] = pack4(acc[ct]);
    // ---- S3: KS = agent @ Wk_s (held to S12) ----
    mmT8(xa, wts + 7 * 16384, m, quad, acc);
#pragma unroll
    for (int ct = 0; ct < 8; ++ct) ksf[ct] = pack4(acc[ct]);
    // ---- S4: Q = selected @ Wq ----
    mmT8(xsk, wts + 0 * 16384, m, quad, acc);
#pragma unroll
    for (int ct = 0; ct < 8; ++ct) qf[ct] = pack4(acc[ct]);

    // ---- S5: 8-head attention, all in registers ----
    // sc = mfma16(K,Q): sc[r] = S[q=m][k=quad*4+r]; P stays in A-frag layout;
    // o  = mfma16(V,P): o[r] = O[m][h*16+quad*4+r] (col-group) -> LDS re-layout.
    {
        const f32x4 z4 = {0.f, 0.f, 0.f, 0.f};
#pragma unroll
        for (int h = 0; h < 8; ++h) {
            f32x4 sc = __builtin_amdgcn_mfma_f32_16x16x16bf16_1k(kf[h], qf[h], z4, 0, 0, 0);
            float e[4], s = 0.f;
#pragma unroll
            for (int r = 0; r < 4; ++r) {
                // scores tiny (|s|<~1): softmax without max-sub is exact enough
                e[r] = keep[r] ? __expf(sc[r] * 0.25f) : 0.f;
                s += e[r];
            }
            s += __shfl_xor(s, 16, 64);
            s += __shfl_xor(s, 32, 64);
            float inv = __builtin_amdgcn_rcpf(s);
            f32x4 p;
#pragma unroll
            for (int r = 0; r < 4; ++r) p[r] = e[r] * inv;
            short4v pa = pack4(p);
            f32x4 o4 = __builtin_amdgcn_mfma_f32_16x16x16bf16_1k(vf[h], pa, z4, 0, 0, 0);
            *(short4v*)(sb + m * LDK + h * 16 + quad * 4) = pack4(o4);
        }
    }
    bfrag xo[4];
#pragma unroll
    for (int kk = 0; kk < 4; ++kk)
        xo[kk] = *(const bfrag*)(sb + m * LDK + kk * 32 + quad * 8);

    // ---- S6: Y = O @ Wo + selected (f32, col-group) ----
    mmT8(xo, wts + 3 * 16384, m, quad, acc);
#pragma unroll
    for (int ct = 0; ct < 8; ++ct)
#pragma unroll
        for (int r = 0; r < 4; ++r) acc[ct][r] += b2f(xsr[ct][r]);

    // ---- S7: LN1 in registers -> H (bf16 col-group, kept for S9 residual) ----
    short4v hf[8];
    {
        float s = 0.f, s2 = 0.f;
#pragma unroll
        for (int ct = 0; ct < 8; ++ct)
#pragma unroll
            for (int r = 0; r < 4; ++r) { float v = acc[ct][r]; s += v; s2 += v * v; }
        s += __shfl_xor(s, 16, 64);  s += __shfl_xor(s, 32, 64);
        s2 += __shfl_xor(s2, 16, 64); s2 += __shfl_xor(s2, 32, 64);
        float mu = s * (1.f / 128.f);
        float var = s2 * (1.f / 128.f) - mu * mu;
        float rs = rsqrtf(var + 1e-5f);
#pragma unroll
        for (int ct = 0; ct < 8; ++ct) {
            f32x4 g4 = *(const f32x4*)(ln1g + ct * 16 + quad * 4);
            f32x4 bb4 = *(const f32x4*)(ln1b + ct * 16 + quad * 4);
            f32x4 hh;
#pragma unroll
            for (int r = 0; r < 4; ++r) hh[r] = (acc[ct][r] - mu) * rs * g4[r] + bb4[r];
            hf[ct] = pack4(hh);
            *(short4v*)(sb + m * LDK + ct * 16 + quad * 4) = hf[ct];
        }
    }
    bfrag hx[4];
#pragma unroll
    for (int kk = 0; kk < 4; ++kk)
        hx[kk] = *(const bfrag*)(sb + m * LDK + kk * 32 + quad * 8);

    // ---- S8: F1 = relu(H @ W1 + b1) ----
    mmT8(hx, wts + 4 * 16384, m, quad, acc);
#pragma unroll
    for (int ct = 0; ct < 8; ++ct) {
        f32x4 bb4 = *(const f32x4*)(b1 + ct * 16 + quad * 4);
        f32x4 f;
#pragma unroll
        for (int r = 0; r < 4; ++r) f[r] = fmaxf(acc[ct][r] + bb4[r], 0.f);
        *(short4v*)(sb + m * LDK + ct * 16 + quad * 4) = pack4(f);
    }
    bfrag fx[4];
#pragma unroll
    for (int kk = 0; kk < 4; ++kk)
        fx[kk] = *(const bfrag*)(sb + m * LDK + kk * 32 + quad * 8);

    // ---- S9: Z = H + F1 @ W2 + b2 ----
    mmT8(fx, wts + 5 * 16384, m, quad, acc);
#pragma unroll
    for (int ct = 0; ct < 8; ++ct) {
        f32x4 bb4 = *(const f32x4*)(b2 + ct * 16 + quad * 4);
#pragma unroll
        for (int r = 0; r < 4; ++r) acc[ct][r] += bb4[r] + b2f(hf[ct][r]);
    }

    // ---- S10: LN2 in registers -> CAC ----
    {
        float s = 0.f, s2 = 0.f;
#pragma unroll
        for (int ct = 0; ct < 8; ++ct)
#pragma unroll
            for (int r = 0; r < 4; ++r) { float v = acc[ct][r]; s += v; s2 += v * v; }
        s += __shfl_xor(s, 16, 64);  s += __shfl_xor(s, 32, 64);
        s2 += __shfl_xor(s2, 16, 64); s2 += __shfl_xor(s2, 32, 64);
        float mu = s * (1.f / 128.f);
        float var = s2 * (1.f / 128.f) - mu * mu;
        float rs = rsqrtf(var + 1e-5f);
#pragma unroll
        for (int ct = 0; ct < 8; ++ct) {
            f32x4 g4 = *(const f32x4*)(ln2g + ct * 16 + quad * 4);
            f32x4 bb4 = *(const f32x4*)(ln2b + ct * 16 + quad * 4);
            f32x4 cc;
#pragma unroll
            for (int r = 0; r < 4; ++r) cc[r] = (acc[ct][r] - mu) * rs * g4[r] + bb4[r];
            *(short4v*)(sb + m * LDK + ct * 16 + quad * 4) = pack4(cc);
        }
    }
    bfrag cx[4];
#pragma unroll
    for (int kk = 0; kk < 4; ++kk)
        cx[kk] = *(const bfrag*)(sb + m * LDK + kk * 32 + quad * 8);

    // ---- S11: QS = CAC @ Wq_s ----
    mmT8(cx, wts + 6 * 16384, m, quad, acc);
    short4v qsf[8];
#pragma unroll
    for (int ct = 0; ct < 8; ++ct) qsf[ct] = pack4(acc[ct]);

    // ---- S12: logits = 10*tanh(QS @ KS^T / sqrt(128)), mask, store ----
    // la = sum_ct mfma16(KS,QS): la[r] = logits[q=m][k'=quad*4+r]
    {
        f32x4 la = {0.f, 0.f, 0.f, 0.f};
#pragma unroll
        for (int ct = 0; ct < 8; ++ct)
            la = __builtin_amdgcn_mfma_f32_16x16x16bf16_1k(ksf[ct], qsf[ct], la, 0, 0, 0);
        f32x4 o4;
#pragma unroll
        for (int r = 0; r < 4; ++r) {
            float v = la[r] * 0.0883883476483184f;  // 1/sqrt(128)
            v = 10.f * tanhf(v);
            o4[r] = keep[r] ? v : -1e9f;
        }
        *(f32x4*)(out + ((size_t)b * 16 + m) * 16 + quad * 4) = o4;
    }
}

extern "C" void kernel_launch(void* const* d_in, const int* in_sizes, int n_in,
                              void* d_out, int out_size, void* d_ws, size_t ws_size,
                              hipStream_t stream)
{
    const float* agent = (const float*)d_in[0];
    const float* city  = (const float*)d_in[1];
    const int*   acts  = (const int*)d_in[2];
    const float* Wq  = (const float*)d_in[3];
    const float* Wk  = (const float*)d_in[4];
    const float* Wv  = (const float*)d_in[5];
    const float* Wo  = (const float*)d_in[6];
    const float* l1g = (const float*)d_in[7];
    const float* l1b = (const float*)d_in[8];
    const float* W1  = (const float*)d_in[9];
    const float* b1  = (const float*)d_in[10];
    const float* W2  = (const float*)d_in[11];
    const float* b2  = (const float*)d_in[12];
    const float* l2g = (const float*)d_in[13];
    const float* l2b = (const float*)d_in[14];
    const float* Wqs = (const float*)d_in[15];
    const float* Wks = (const float*)d_in[16];
    float* out = (float*)d_out;

    int B = in_sizes[2] / 16;  // acts is [B,16]
    __hip_bfloat16* wts = (__hip_bfloat16*)d_ws;  // 8*16384 bf16 = 256 KB

    prep_weights<<<64, 256, 0, stream>>>(Wq, Wk, Wv, Wo, W1, W2, Wqs, Wks, wts);
    fused_model<<<B, 64, 0, stream>>>(agent, city, acts, wts, l1g, l1b,
                                      b1, b2, l2g, l2b, out);
}